// Round 16
// baseline (202.191 us; speedup 1.0000x reference)
//
#include <hip/hip_runtime.h>
#include <hip/hip_bf16.h>
#include <stdint.h>

typedef __bf16 bf16_t;
typedef __attribute__((ext_vector_type(8))) __bf16 bf16x8;
typedef __attribute__((ext_vector_type(4))) __bf16 bf16x4v;
typedef __attribute__((ext_vector_type(4))) float f32x4;

#define GLOBAL_AS __attribute__((address_space(1)))
#define LDS_AS __attribute__((address_space(3)))

__device__ __forceinline__ void gload_lds16(const bf16_t* g, bf16_t* l) {
  __builtin_amdgcn_global_load_lds((const GLOBAL_AS void*)g, (LDS_AS void*)l, 16, 0, 0);
}

__device__ __forceinline__ uint32_t pk2(float a, float b) {
  union { bf16_t h[2]; uint32_t u; } x;
  x.h[0] = (bf16_t)a; x.h[1] = (bf16_t)b;
  return x.u;
}

// 8x8 bf16 transpose across lanes within 8-lane groups (lane bits 0..2).
__device__ __forceinline__ bf16x8 xpose8(bf16x8 v, int l) {
  union { bf16x8 v; uint32_t u[4]; } tv; tv.v = v;
  uint32_t a0 = __shfl_xor((int)tv.u[2], 4, 64);
  uint32_t a1 = __shfl_xor((int)tv.u[3], 4, 64);
  uint32_t a2 = __shfl_xor((int)tv.u[0], 4, 64);
  uint32_t a3 = __shfl_xor((int)tv.u[1], 4, 64);
  bool s4 = (l & 4) != 0;
  uint32_t n0 = s4 ? a0 : tv.u[0];
  uint32_t n1 = s4 ? a1 : tv.u[1];
  uint32_t n2 = s4 ? tv.u[2] : a2;
  uint32_t n3 = s4 ? tv.u[3] : a3;
  uint32_t b0 = __shfl_xor((int)n1, 2, 64);
  uint32_t b1 = __shfl_xor((int)n0, 2, 64);
  uint32_t b2 = __shfl_xor((int)n3, 2, 64);
  uint32_t b3 = __shfl_xor((int)n2, 2, 64);
  bool s2 = (l & 2) != 0;
  uint32_t m0 = s2 ? b0 : n0;
  uint32_t m1 = s2 ? n1 : b1;
  uint32_t m2 = s2 ? b2 : n2;
  uint32_t m3 = s2 ? n3 : b3;
  uint32_t c0 = __shfl_xor((int)m0, 1, 64);
  uint32_t c1 = __shfl_xor((int)m1, 1, 64);
  uint32_t c2 = __shfl_xor((int)m2, 1, 64);
  uint32_t c3 = __shfl_xor((int)m3, 1, 64);
  bool odd = (l & 1) != 0;
  union { uint32_t u[4]; bf16x8 v; } tw;
  tw.u[0] = odd ? ((m0 & 0xFFFF0000u) | (c0 >> 16)) : ((m0 & 0xFFFFu) | (c0 << 16));
  tw.u[1] = odd ? ((m1 & 0xFFFF0000u) | (c1 >> 16)) : ((m1 & 0xFFFFu) | (c1 << 16));
  tw.u[2] = odd ? ((m2 & 0xFFFF0000u) | (c2 >> 16)) : ((m2 & 0xFFFFu) | (c2 << 16));
  tw.u[3] = odd ? ((m3 & 0xFFFF0000u) | (c3 >> 16)) : ((m3 & 0xFFFFu) | (c3 << 16));
  return tw.v;
}

// ---------------------------------------------------------------- convert (fused, 8 elems/thread)
__global__ void cvt3_f32_bf16(const float* __restrict__ x, const float* __restrict__ wq,
                              const float* __restrict__ wo, bf16_t* __restrict__ out) {
  int i = (blockIdx.x * 256 + threadIdx.x) * 8;
  const float* src;
  int off;
  if (i < 4194304)      { src = x;  off = 0; }
  else if (i < 7340032) { src = wq; off = 4194304; }
  else                  { src = wo; off = 7340032; }
  const float* p = src + (i - off);
  float4 v0 = *(const float4*)(p);
  float4 v1 = *(const float4*)(p + 4);
  bf16x8 o;
  o[0] = (bf16_t)v0.x; o[1] = (bf16_t)v0.y; o[2] = (bf16_t)v0.z; o[3] = (bf16_t)v0.w;
  o[4] = (bf16_t)v1.x; o[5] = (bf16_t)v1.y; o[6] = (bf16_t)v1.z; o[7] = (bf16_t)v1.w;
  *(bf16x8*)(out + i) = o;
}

// ---------------------------------------------------------------- GEMM TN (128x128, bf16 out)
// 2D XCD swizzle: each XCD owns an 8-brow x 12-bcol rectangle.
__global__ __launch_bounds__(256)
void gemm_tn(const bf16_t* __restrict__ A, const bf16_t* __restrict__ B,
             bf16_t* __restrict__ Cout, int K, int ldc, int qcols, float qscale)
{
  __shared__ __align__(16) bf16_t As[128 * 32];
  __shared__ __align__(16) bf16_t Bs[128 * 32];
  const int t  = threadIdx.x;
  const int l  = t & 63, w = t >> 6;
  const int wm = w >> 1, wn = w & 1;
  const int lo = l & 15, hi = l >> 4;
  const int o = (int)blockIdx.x;
  const int xcd = o & 7, i = o >> 3;       // i: 0..95
  const int brow = ((xcd >> 1) * 8 + i / 12) * 128;
  const int bcol = ((xcd & 1) * 12 + i % 12) * 128;

  const int i0 = t, i1 = t + 256;
  const int r0 = i0 >> 2, c0 = i0 & 3;
  const int r1 = i1 >> 2, c1 = i1 & 3;

  f32x4 acc[4][4] = {};

  for (int k0 = 0; k0 < K; k0 += 32) {
    gload_lds16(A + (size_t)(brow + r0) * K + k0 + c0 * 8, As + i0 * 8);
    gload_lds16(A + (size_t)(brow + r1) * K + k0 + c1 * 8, As + i1 * 8);
    gload_lds16(B + (size_t)(bcol + r0) * K + k0 + c0 * 8, Bs + i0 * 8);
    gload_lds16(B + (size_t)(bcol + r1) * K + k0 + c1 * 8, Bs + i1 * 8);
    __syncthreads();

    bf16x8 a[4], bb[4];
#pragma unroll
    for (int fm = 0; fm < 4; fm++)
      a[fm] = *(const bf16x8*)(As + (wm * 64 + fm * 16 + lo) * 32 + hi * 8);
#pragma unroll
    for (int fn = 0; fn < 4; fn++)
      bb[fn] = *(const bf16x8*)(Bs + (wn * 64 + fn * 16 + lo) * 32 + hi * 8);

#pragma unroll
    for (int fm = 0; fm < 4; fm++)
#pragma unroll
      for (int fn = 0; fn < 4; fn++)
        acc[fm][fn] = __builtin_amdgcn_mfma_f32_16x16x32_bf16(a[fm], bb[fn], acc[fm][fn], 0, 0, 0);
    __syncthreads();
  }

#pragma unroll
  for (int fm = 0; fm < 4; fm++) {
#pragma unroll
    for (int fn = 0; fn < 4; fn++) {
#pragma unroll
      for (int j = 0; j < 4; j++) {
        int row = brow + wm * 64 + fm * 16 + hi * 4 + j;
        int col = bcol + wn * 64 + fn * 16 + lo;
        float v = acc[fm][fn][j];
        if (col < qcols) v *= qscale;
        Cout[(size_t)row * ldc + col] = (bf16_t)v;
      }
    }
  }
}

// ---------------------------------------------------------------- GEMM TN (128x64, f32 out + bias)
__global__ __launch_bounds__(256, 4)
void gemm_tn_n64(const bf16_t* __restrict__ A, const bf16_t* __restrict__ B,
                 float* __restrict__ Cout, const float* __restrict__ bias,
                 int K, int ldc)
{
  __shared__ __align__(16) bf16_t As[128 * 32];
  __shared__ __align__(16) bf16_t Bs[64 * 32];
  const int t  = threadIdx.x;
  const int l  = t & 63, w = t >> 6;
  const int wm = w >> 1, wn = w & 1;
  const int lo = l & 15, hi = l >> 4;
  const int o = (int)blockIdx.x;
  const int xcd = o & 7, i = o >> 3;       // i: 0..63
  const int brow = ((xcd >> 1) * 8 + (i >> 3)) * 128;
  const int bcol = ((xcd & 1) * 8 + (i & 7)) * 64;

  const int i0 = t, i1 = t + 256;
  const int r0 = i0 >> 2, c0 = i0 & 3;
  const int r1 = i1 >> 2, c1 = i1 & 3;
  const int rb = t >> 2, cb = t & 3;

  f32x4 acc[4][2] = {};

  for (int k0 = 0; k0 < K; k0 += 32) {
    gload_lds16(A + (size_t)(brow + r0) * K + k0 + c0 * 8, As + i0 * 8);
    gload_lds16(A + (size_t)(brow + r1) * K + k0 + c1 * 8, As + i1 * 8);
    gload_lds16(B + (size_t)(bcol + rb) * K + k0 + cb * 8, Bs + t * 8);
    __syncthreads();

    bf16x8 a[4], bb[2];
#pragma unroll
    for (int fm = 0; fm < 4; fm++)
      a[fm] = *(const bf16x8*)(As + (wm * 64 + fm * 16 + lo) * 32 + hi * 8);
#pragma unroll
    for (int fn = 0; fn < 2; fn++)
      bb[fn] = *(const bf16x8*)(Bs + (wn * 32 + fn * 16 + lo) * 32 + hi * 8);

#pragma unroll
    for (int fm = 0; fm < 4; fm++)
#pragma unroll
      for (int fn = 0; fn < 2; fn++)
        acc[fm][fn] = __builtin_amdgcn_mfma_f32_16x16x32_bf16(a[fm], bb[fn], acc[fm][fn], 0, 0, 0);
    __syncthreads();
  }

#pragma unroll
  for (int fm = 0; fm < 4; fm++) {
#pragma unroll
    for (int fn = 0; fn < 2; fn++) {
#pragma unroll
      for (int j = 0; j < 4; j++) {
        int row = brow + wm * 64 + fm * 16 + hi * 4 + j;
        int col = bcol + wn * 32 + fn * 16 + lo;
        Cout[(size_t)row * ldc + col] = acc[fm][fn][j] + bias[col];
      }
    }
  }
}

// ---------------------------------------------------------------- flash attention (K-bypass)
// qkv: [4096, 3072] bf16; Q pre-scaled by 0.125*log2(e).  8 waves x 16
// q-rows, KVBLK=128 (2 x 64-key halves), 16 iterations.
// K fragments read DIRECTLY from global (L1-resident: 16KB tile shared by
// all 8 waves; L2-resident across the 16 q-blocks of a head) — m169
// precedent: don't LDS-stage cache-fit data.  V still staged+transposed
// (kappa-order, double-buffered, stride 136 = b128 bank floor); barrier
// protects V staging only.  P packed in-register under
// kappa(kb,hi,e) = (2kb+(e>>2))*16+hi*4+(e&3) per half.
#define LDKV 136

__global__ __launch_bounds__(512, 2)
void flash_attn(const bf16_t* __restrict__ qkv, bf16_t* __restrict__ aout)
{
  __shared__ __align__(16) bf16_t Vt[2][64 * LDKV];

  const int t = threadIdx.x;
  const int l = t & 63, w = t >> 6;
  const int lo = l & 15, hi = l >> 4;
  int bid = (int)blockIdx.x;
  bid = (bid & 7) * 64 + (bid >> 3);
  const int qblk = bid & 15;
  const int bh   = bid >> 4;
  const int b = bh >> 4, h = bh & 15;
  const int rowbase = b * 2048;
  const int q0 = qblk * 128 + w * 16;

  const int r = l & 7, c = l >> 3;
  const int vkey = 32 * (w >> 2) + 16 * (r >> 2) + 4 * (w & 3) + (r & 3);
  const bf16_t* kvbase = qkv + (size_t)rowbase * 3072 + h * 64 + 1024;
  const size_t step = (size_t)128 * 3072;

  bf16x8 aq[2];
#pragma unroll
  for (int kb = 0; kb < 2; kb++)
    aq[kb] = *(const bf16x8*)(qkv + (size_t)(rowbase + q0 + lo) * 3072
                              + h * 64 + kb * 32 + hi * 8);

  bf16x8 ones;
#pragma unroll
  for (int j = 0; j < 8; j++) ones[j] = (bf16_t)1.0f;

  f32x4 oacc[4] = {};
  f32x4 ssum = {};

  // ---- prologue: V tile 0 -> buf0, prefetch V tile 1 into regs ----
  bf16x8 vch[2];
#pragma unroll
  for (int i = 0; i < 2; i++)
    vch[i] = *(const bf16x8*)(kvbase + 1024 + (size_t)(vkey + 64 * i) * 3072 + c * 8);
#pragma unroll
  for (int i = 0; i < 2; i++)
    *(bf16x8*)(&Vt[0][0] + (c * 8 + r) * LDKV + 64 * i + w * 8) = xpose8(vch[i], l);
  const bf16_t* kv_next = kvbase + step;
#pragma unroll
  for (int i = 0; i < 2; i++)
    vch[i] = *(const bf16x8*)(kv_next + 1024 + (size_t)(vkey + 64 * i) * 3072 + c * 8);
  kv_next += step;

  for (int it = 0; it < 16; ++it) {
    __syncthreads();
    const int cur = it & 1;
    bf16_t* VtN = &Vt[cur ^ 1][0];
    const bf16_t* VtC = &Vt[cur][0];
    const bf16_t* ktile = kvbase + (size_t)it * step;   // K rows for this iter

    // stage V tile it+1 (regs already loaded) into the other buffer
    if (it < 15) {
#pragma unroll
      for (int i = 0; i < 2; i++)
        *(bf16x8*)(VtN + (c * 8 + r) * LDKV + 64 * i + w * 8) = xpose8(vch[i], l);
    }
    // prefetch V tile it+2 into regs
    if (it < 14) {
#pragma unroll
      for (int i = 0; i < 2; i++)
        vch[i] = *(const bf16x8*)(kv_next + 1024 + (size_t)(vkey + 64 * i) * 3072 + c * 8);
      kv_next += step;
    }

#pragma unroll
    for (int h2 = 0; h2 < 2; h2++) {
      // ---- QK^T (swapped: K as A, Q as B); K read direct from global ----
      bf16x8 kf[4][2];
#pragma unroll
      for (int fn = 0; fn < 4; fn++)
#pragma unroll
        for (int kb = 0; kb < 2; kb++)
          kf[fn][kb] = *(const bf16x8*)(ktile + (size_t)(64 * h2 + fn * 16 + lo) * 3072
                                        + kb * 32 + hi * 8);
      f32x4 sacc[4] = {};
#pragma unroll
      for (int fn = 0; fn < 4; fn++)
#pragma unroll
        for (int kb = 0; kb < 2; kb++)
          sacc[fn] = __builtin_amdgcn_mfma_f32_16x16x32_bf16(kf[fn][kb], aq[kb], sacc[fn], 0, 0, 0);

      float p[4][4];
#pragma unroll
      for (int fn = 0; fn < 4; fn++)
#pragma unroll
        for (int j = 0; j < 4; j++)
          p[fn][j] = __builtin_amdgcn_exp2f(sacc[fn][j]);
      bf16x8 pa[2];
#pragma unroll
      for (int kb = 0; kb < 2; kb++) {
        union { uint32_t u[4]; bf16x8 v; } pw;
        pw.u[0] = pk2(p[2 * kb][0],     p[2 * kb][1]);
        pw.u[1] = pk2(p[2 * kb][2],     p[2 * kb][3]);
        pw.u[2] = pk2(p[2 * kb + 1][0], p[2 * kb + 1][1]);
        pw.u[3] = pk2(p[2 * kb + 1][2], p[2 * kb + 1][3]);
        pa[kb] = pw.v;
      }

      bf16x8 vb[4][2];
#pragma unroll
      for (int fd = 0; fd < 4; fd++)
#pragma unroll
        for (int kb = 0; kb < 2; kb++)
          vb[fd][kb] = *(const bf16x8*)(VtC + (fd * 16 + lo) * LDKV + 64 * h2 + kb * 32 + hi * 8);
#pragma unroll
      for (int kb = 0; kb < 2; kb++)
        ssum = __builtin_amdgcn_mfma_f32_16x16x32_bf16(pa[kb], ones, ssum, 0, 0, 0);
#pragma unroll
      for (int fd = 0; fd < 4; fd++)
#pragma unroll
        for (int kb = 0; kb < 2; kb++)
          oacc[fd] = __builtin_amdgcn_mfma_f32_16x16x32_bf16(pa[kb], vb[fd][kb], oacc[fd], 0, 0, 0);
    }
  }

#pragma unroll
  for (int j = 0; j < 4; j++) {
    float inv = 1.0f / ssum[j];
    int row = rowbase + q0 + hi * 4 + j;
#pragma unroll
    for (int fd = 0; fd < 4; fd++) {
      int col = h * 64 + fd * 16 + lo;
      aout[(size_t)row * 1024 + col] = (bf16_t)(oacc[fd][j] * inv);
    }
  }
}

// ---------------------------------------------------------------- launch
extern "C" void kernel_launch(void* const* d_in, const int* in_sizes, int n_in,
                              void* d_out, int out_size, void* d_ws, size_t ws_size,
                              hipStream_t stream) {
  const float* x     = (const float*)d_in[0];
  const float* w_qkv = (const float*)d_in[1];
  const float* w_out = (const float*)d_in[2];
  const float* b_out = (const float*)d_in[3];

  char* ws = (char*)d_ws;
  bf16_t* xb   = (bf16_t*)(ws);                       // 4096*1024  (8 MB)
  bf16_t* wqb  = (bf16_t*)(ws + 8388608);             // 3072*1024  (6 MB)
  bf16_t* wob  = (bf16_t*)(ws + 14680064);            // 1024*1024  (2 MB)
  bf16_t* qkvb = (bf16_t*)(ws + 16777216);            // 4096*3072  (24 MB)
  bf16_t* aob  = (bf16_t*)(ws + 41943040);            // 4096*1024  (8 MB)

  cvt3_f32_bf16<<<4096, 256, 0, stream>>>(x, w_qkv, w_out, xb);

  // gemm1: M=4096 N=3072 -> 32x24 = 768 blocks, 8x12 rectangle per XCD
  gemm_tn<<<768, 256, 0, stream>>>(xb, wqb, qkvb, 1024, 3072,
                                   1024, 0.18033688011f);

  flash_attn<<<512, 512, 0, stream>>>(qkvb, aob);

  // gemm2: M=4096 N=1024, BN=64 -> 32x16 = 512 blocks, 8x8 rectangle per XCD
  gemm_tn_n64<<<512, 256, 0, stream>>>(aob, wob, (float*)d_out, b_out,
                                       1024, 1024);
}

// Round 17
// 128.599 us; speedup vs baseline: 1.5723x; 1.5723x over previous
//
#include <hip/hip_runtime.h>
#include <hip/hip_bf16.h>
#include <stdint.h>

typedef __bf16 bf16_t;
typedef __attribute__((ext_vector_type(8))) __bf16 bf16x8;
typedef __attribute__((ext_vector_type(4))) __bf16 bf16x4v;
typedef __attribute__((ext_vector_type(4))) float f32x4;

#define GLOBAL_AS __attribute__((address_space(1)))
#define LDS_AS __attribute__((address_space(3)))

__device__ __forceinline__ void gload_lds16(const bf16_t* g, bf16_t* l) {
  __builtin_amdgcn_global_load_lds((const GLOBAL_AS void*)g, (LDS_AS void*)l, 16, 0, 0);
}

__device__ __forceinline__ uint32_t pk2(float a, float b) {
  union { bf16_t h[2]; uint32_t u; } x;
  x.h[0] = (bf16_t)a; x.h[1] = (bf16_t)b;
  return x.u;
}

// 8x8 bf16 transpose across lanes within 8-lane groups (lane bits 0..2).
__device__ __forceinline__ bf16x8 xpose8(bf16x8 v, int l) {
  union { bf16x8 v; uint32_t u[4]; } tv; tv.v = v;
  uint32_t a0 = __shfl_xor((int)tv.u[2], 4, 64);
  uint32_t a1 = __shfl_xor((int)tv.u[3], 4, 64);
  uint32_t a2 = __shfl_xor((int)tv.u[0], 4, 64);
  uint32_t a3 = __shfl_xor((int)tv.u[1], 4, 64);
  bool s4 = (l & 4) != 0;
  uint32_t n0 = s4 ? a0 : tv.u[0];
  uint32_t n1 = s4 ? a1 : tv.u[1];
  uint32_t n2 = s4 ? tv.u[2] : a2;
  uint32_t n3 = s4 ? tv.u[3] : a3;
  uint32_t b0 = __shfl_xor((int)n1, 2, 64);
  uint32_t b1 = __shfl_xor((int)n0, 2, 64);
  uint32_t b2 = __shfl_xor((int)n3, 2, 64);
  uint32_t b3 = __shfl_xor((int)n2, 2, 64);
  bool s2 = (l & 2) != 0;
  uint32_t m0 = s2 ? b0 : n0;
  uint32_t m1 = s2 ? n1 : b1;
  uint32_t m2 = s2 ? b2 : n2;
  uint32_t m3 = s2 ? n3 : b3;
  uint32_t c0 = __shfl_xor((int)m0, 1, 64);
  uint32_t c1 = __shfl_xor((int)m1, 1, 64);
  uint32_t c2 = __shfl_xor((int)m2, 1, 64);
  uint32_t c3 = __shfl_xor((int)m3, 1, 64);
  bool odd = (l & 1) != 0;
  union { uint32_t u[4]; bf16x8 v; } tw;
  tw.u[0] = odd ? ((m0 & 0xFFFF0000u) | (c0 >> 16)) : ((m0 & 0xFFFFu) | (c0 << 16));
  tw.u[1] = odd ? ((m1 & 0xFFFF0000u) | (c1 >> 16)) : ((m1 & 0xFFFFu) | (c1 << 16));
  tw.u[2] = odd ? ((m2 & 0xFFFF0000u) | (c2 >> 16)) : ((m2 & 0xFFFFu) | (c2 << 16));
  tw.u[3] = odd ? ((m3 & 0xFFFF0000u) | (c3 >> 16)) : ((m3 & 0xFFFFu) | (c3 << 16));
  return tw.v;
}

// ---------------------------------------------------------------- convert (fused, 8 elems/thread)
__global__ void cvt3_f32_bf16(const float* __restrict__ x, const float* __restrict__ wq,
                              const float* __restrict__ wo, bf16_t* __restrict__ out) {
  int i = (blockIdx.x * 256 + threadIdx.x) * 8;
  const float* src;
  int off;
  if (i < 4194304)      { src = x;  off = 0; }
  else if (i < 7340032) { src = wq; off = 4194304; }
  else                  { src = wo; off = 7340032; }
  const float* p = src + (i - off);
  float4 v0 = *(const float4*)(p);
  float4 v1 = *(const float4*)(p + 4);
  bf16x8 o;
  o[0] = (bf16_t)v0.x; o[1] = (bf16_t)v0.y; o[2] = (bf16_t)v0.z; o[3] = (bf16_t)v0.w;
  o[4] = (bf16_t)v1.x; o[5] = (bf16_t)v1.y; o[6] = (bf16_t)v1.z; o[7] = (bf16_t)v1.w;
  *(bf16x8*)(out + i) = o;
}

// ---------------------------------------------------------------- GEMM TN (128x128, bf16 out)
// 2D XCD swizzle: each XCD owns an 8-brow x 12-bcol rectangle
// (A-panel 2MB + B-panel 3MB ~ fits the 4MB per-XCD L2).
__global__ __launch_bounds__(256)
void gemm_tn(const bf16_t* __restrict__ A, const bf16_t* __restrict__ B,
             bf16_t* __restrict__ Cout, int K, int ldc, int qcols, float qscale)
{
  __shared__ __align__(16) bf16_t As[128 * 32];
  __shared__ __align__(16) bf16_t Bs[128 * 32];
  const int t  = threadIdx.x;
  const int l  = t & 63, w = t >> 6;
  const int wm = w >> 1, wn = w & 1;
  const int lo = l & 15, hi = l >> 4;
  const int o = (int)blockIdx.x;
  const int xcd = o & 7, i = o >> 3;       // i: 0..95
  const int brow = ((xcd >> 1) * 8 + i / 12) * 128;
  const int bcol = ((xcd & 1) * 12 + i % 12) * 128;

  const int i0 = t, i1 = t + 256;
  const int r0 = i0 >> 2, c0 = i0 & 3;
  const int r1 = i1 >> 2, c1 = i1 & 3;

  f32x4 acc[4][4] = {};

  for (int k0 = 0; k0 < K; k0 += 32) {
    gload_lds16(A + (size_t)(brow + r0) * K + k0 + c0 * 8, As + i0 * 8);
    gload_lds16(A + (size_t)(brow + r1) * K + k0 + c1 * 8, As + i1 * 8);
    gload_lds16(B + (size_t)(bcol + r0) * K + k0 + c0 * 8, Bs + i0 * 8);
    gload_lds16(B + (size_t)(bcol + r1) * K + k0 + c1 * 8, Bs + i1 * 8);
    __syncthreads();

    bf16x8 a[4], bb[4];
#pragma unroll
    for (int fm = 0; fm < 4; fm++)
      a[fm] = *(const bf16x8*)(As + (wm * 64 + fm * 16 + lo) * 32 + hi * 8);
#pragma unroll
    for (int fn = 0; fn < 4; fn++)
      bb[fn] = *(const bf16x8*)(Bs + (wn * 64 + fn * 16 + lo) * 32 + hi * 8);

#pragma unroll
    for (int fm = 0; fm < 4; fm++)
#pragma unroll
      for (int fn = 0; fn < 4; fn++)
        acc[fm][fn] = __builtin_amdgcn_mfma_f32_16x16x32_bf16(a[fm], bb[fn], acc[fm][fn], 0, 0, 0);
    __syncthreads();
  }

#pragma unroll
  for (int fm = 0; fm < 4; fm++) {
#pragma unroll
    for (int fn = 0; fn < 4; fn++) {
#pragma unroll
      for (int j = 0; j < 4; j++) {
        int row = brow + wm * 64 + fm * 16 + hi * 4 + j;
        int col = bcol + wn * 64 + fn * 16 + lo;
        float v = acc[fm][fn][j];
        if (col < qcols) v *= qscale;
        Cout[(size_t)row * ldc + col] = (bf16_t)v;
      }
    }
  }
}

// ---------------------------------------------------------------- GEMM TN (128x64, f32 out + bias)
// BN=64 => 512 blocks = 2 blocks/CU.  2D XCD swizzle: 8-brow x 8-bcol
// rectangle per XCD (A 2MB + B 1MB = fully L2-resident).
__global__ __launch_bounds__(256, 4)
void gemm_tn_n64(const bf16_t* __restrict__ A, const bf16_t* __restrict__ B,
                 float* __restrict__ Cout, const float* __restrict__ bias,
                 int K, int ldc)
{
  __shared__ __align__(16) bf16_t As[128 * 32];
  __shared__ __align__(16) bf16_t Bs[64 * 32];
  const int t  = threadIdx.x;
  const int l  = t & 63, w = t >> 6;
  const int wm = w >> 1, wn = w & 1;
  const int lo = l & 15, hi = l >> 4;
  const int o = (int)blockIdx.x;
  const int xcd = o & 7, i = o >> 3;       // i: 0..63
  const int brow = ((xcd >> 1) * 8 + (i >> 3)) * 128;
  const int bcol = ((xcd & 1) * 8 + (i & 7)) * 64;

  const int i0 = t, i1 = t + 256;          // A chunks: 512 total
  const int r0 = i0 >> 2, c0 = i0 & 3;
  const int r1 = i1 >> 2, c1 = i1 & 3;
  const int rb = t >> 2, cb = t & 3;       // B chunks: 256 total, 1/thread

  f32x4 acc[4][2] = {};

  for (int k0 = 0; k0 < K; k0 += 32) {
    gload_lds16(A + (size_t)(brow + r0) * K + k0 + c0 * 8, As + i0 * 8);
    gload_lds16(A + (size_t)(brow + r1) * K + k0 + c1 * 8, As + i1 * 8);
    gload_lds16(B + (size_t)(bcol + rb) * K + k0 + cb * 8, Bs + t * 8);
    __syncthreads();

    bf16x8 a[4], bb[2];
#pragma unroll
    for (int fm = 0; fm < 4; fm++)
      a[fm] = *(const bf16x8*)(As + (wm * 64 + fm * 16 + lo) * 32 + hi * 8);
#pragma unroll
    for (int fn = 0; fn < 2; fn++)
      bb[fn] = *(const bf16x8*)(Bs + (wn * 32 + fn * 16 + lo) * 32 + hi * 8);

#pragma unroll
    for (int fm = 0; fm < 4; fm++)
#pragma unroll
      for (int fn = 0; fn < 2; fn++)
        acc[fm][fn] = __builtin_amdgcn_mfma_f32_16x16x32_bf16(a[fm], bb[fn], acc[fm][fn], 0, 0, 0);
    __syncthreads();
  }

#pragma unroll
  for (int fm = 0; fm < 4; fm++) {
#pragma unroll
    for (int fn = 0; fn < 2; fn++) {
#pragma unroll
      for (int j = 0; j < 4; j++) {
        int row = brow + wm * 64 + fm * 16 + hi * 4 + j;
        int col = bcol + wn * 32 + fn * 16 + lo;
        Cout[(size_t)row * ldc + col] = acc[fm][fn][j] + bias[col];
      }
    }
  }
}

// ---------------------------------------------------------------- flash attention (frozen, R11/R10 verified)
// qkv: [4096, 3072] bf16; Q pre-scaled by 0.125*log2(e).  8 waves x 16
// q-rows, KVBLK=128 (2 x 64-key halves), 16 iterations.  Swapped QK^T;
// P packed in-register under kappa(kb,hi,e) = (2kb+(e>>2))*16+hi*4+(e&3)
// per half; V staged into kappa-order.  Double-buffered; Kl stride 72,
// Vt stride 136 (b128 bank floor).  K LDS-staging is load-bearing (R15:
// direct-global K reads are uncoalesced, 2.2x regression).
#define LDK  72
#define LDKV 136

__global__ __launch_bounds__(512, 2)
void flash_attn(const bf16_t* __restrict__ qkv, bf16_t* __restrict__ aout)
{
  __shared__ __align__(16) bf16_t Kl[2][128 * LDK];
  __shared__ __align__(16) bf16_t Vt[2][64 * LDKV];

  const int t = threadIdx.x;
  const int l = t & 63, w = t >> 6;
  const int lo = l & 15, hi = l >> 4;
  int bid = (int)blockIdx.x;
  bid = (bid & 7) * 64 + (bid >> 3);
  const int qblk = bid & 15;
  const int bh   = bid >> 4;
  const int b = bh >> 4, h = bh & 15;
  const int rowbase = b * 2048;
  const int q0 = qblk * 128 + w * 16;

  const int r = l & 7, c = l >> 3;
  const int krow = w * 8 + (l >> 3);
  const int kc   = l & 7;
  const int vkey = 32 * (w >> 2) + 16 * (r >> 2) + 4 * (w & 3) + (r & 3);
  const bf16_t* kvbase = qkv + (size_t)rowbase * 3072 + h * 64 + 1024;
  const size_t step = (size_t)128 * 3072;

  bf16x8 aq[2];
#pragma unroll
  for (int kb = 0; kb < 2; kb++)
    aq[kb] = *(const bf16x8*)(qkv + (size_t)(rowbase + q0 + lo) * 3072
                              + h * 64 + kb * 32 + hi * 8);

  bf16x8 ones;
#pragma unroll
  for (int j = 0; j < 8; j++) ones[j] = (bf16_t)1.0f;

  f32x4 oacc[4] = {};
  f32x4 ssum = {};

  bf16x8 kch[2], vch[2];
#pragma unroll
  for (int i = 0; i < 2; i++) {
    kch[i] = *(const bf16x8*)(kvbase + (size_t)(krow + 64 * i) * 3072 + kc * 8);
    vch[i] = *(const bf16x8*)(kvbase + 1024 + (size_t)(vkey + 64 * i) * 3072 + c * 8);
  }
#pragma unroll
  for (int i = 0; i < 2; i++) {
    *(bf16x8*)(&Kl[0][0] + (krow + 64 * i) * LDK + kc * 8) = kch[i];
    *(bf16x8*)(&Vt[0][0] + (c * 8 + r) * LDKV + 64 * i + w * 8) = xpose8(vch[i], l);
  }
  const bf16_t* kv_next = kvbase + step;
#pragma unroll
  for (int i = 0; i < 2; i++) {
    kch[i] = *(const bf16x8*)(kv_next + (size_t)(krow + 64 * i) * 3072 + kc * 8);
    vch[i] = *(const bf16x8*)(kv_next + 1024 + (size_t)(vkey + 64 * i) * 3072 + c * 8);
  }
  kv_next += step;

  for (int it = 0; it < 16; ++it) {
    __syncthreads();
    const int cur = it & 1;
    bf16_t* KlN = &Kl[cur ^ 1][0];
    bf16_t* VtN = &Vt[cur ^ 1][0];
    const bf16_t* KlC = &Kl[cur][0];
    const bf16_t* VtC = &Vt[cur][0];

    if (it < 15) {
#pragma unroll
      for (int i = 0; i < 2; i++) {
        *(bf16x8*)(KlN + (krow + 64 * i) * LDK + kc * 8) = kch[i];
        *(bf16x8*)(VtN + (c * 8 + r) * LDKV + 64 * i + w * 8) = xpose8(vch[i], l);
      }
    }
    if (it < 14) {
#pragma unroll
      for (int i = 0; i < 2; i++) {
        kch[i] = *(const bf16x8*)(kv_next + (size_t)(krow + 64 * i) * 3072 + kc * 8);
        vch[i] = *(const bf16x8*)(kv_next + 1024 + (size_t)(vkey + 64 * i) * 3072 + c * 8);
      }
      kv_next += step;
    }

#pragma unroll
    for (int h2 = 0; h2 < 2; h2++) {
      bf16x8 kf[4][2];
#pragma unroll
      for (int fn = 0; fn < 4; fn++)
#pragma unroll
        for (int kb = 0; kb < 2; kb++)
          kf[fn][kb] = *(const bf16x8*)(KlC + (64 * h2 + fn * 16 + lo) * LDK + kb * 32 + hi * 8);
      f32x4 sacc[4] = {};
#pragma unroll
      for (int fn = 0; fn < 4; fn++)
#pragma unroll
        for (int kb = 0; kb < 2; kb++)
          sacc[fn] = __builtin_amdgcn_mfma_f32_16x16x32_bf16(kf[fn][kb], aq[kb], sacc[fn], 0, 0, 0);

      float p[4][4];
#pragma unroll
      for (int fn = 0; fn < 4; fn++)
#pragma unroll
        for (int j = 0; j < 4; j++)
          p[fn][j] = __builtin_amdgcn_exp2f(sacc[fn][j]);
      bf16x8 pa[2];
#pragma unroll
      for (int kb = 0; kb < 2; kb++) {
        union { uint32_t u[4]; bf16x8 v; } pw;
        pw.u[0] = pk2(p[2 * kb][0],     p[2 * kb][1]);
        pw.u[1] = pk2(p[2 * kb][2],     p[2 * kb][3]);
        pw.u[2] = pk2(p[2 * kb + 1][0], p[2 * kb + 1][1]);
        pw.u[3] = pk2(p[2 * kb + 1][2], p[2 * kb + 1][3]);
        pa[kb] = pw.v;
      }

      bf16x8 vb[4][2];
#pragma unroll
      for (int fd = 0; fd < 4; fd++)
#pragma unroll
        for (int kb = 0; kb < 2; kb++)
          vb[fd][kb] = *(const bf16x8*)(VtC + (fd * 16 + lo) * LDKV + 64 * h2 + kb * 32 + hi * 8);
#pragma unroll
      for (int kb = 0; kb < 2; kb++)
        ssum = __builtin_amdgcn_mfma_f32_16x16x32_bf16(pa[kb], ones, ssum, 0, 0, 0);
#pragma unroll
      for (int fd = 0; fd < 4; fd++)
#pragma unroll
        for (int kb = 0; kb < 2; kb++)
          oacc[fd] = __builtin_amdgcn_mfma_f32_16x16x32_bf16(pa[kb], vb[fd][kb], oacc[fd], 0, 0, 0);
    }
  }

#pragma unroll
  for (int j = 0; j < 4; j++) {
    float inv = 1.0f / ssum[j];
    int row = rowbase + q0 + hi * 4 + j;
#pragma unroll
    for (int fd = 0; fd < 4; fd++) {
      int col = h * 64 + fd * 16 + lo;
      aout[(size_t)row * 1024 + col] = (bf16_t)(oacc[fd][j] * inv);
    }
  }
}

// ---------------------------------------------------------------- launch
extern "C" void kernel_launch(void* const* d_in, const int* in_sizes, int n_in,
                              void* d_out, int out_size, void* d_ws, size_t ws_size,
                              hipStream_t stream) {
  const float* x     = (const float*)d_in[0];
  const float* w_qkv = (const float*)d_in[1];
  const float* w_out = (const float*)d_in[2];
  const float* b_out = (const float*)d_in[3];

  char* ws = (char*)d_ws;
  bf16_t* xb   = (bf16_t*)(ws);                       // 4096*1024  (8 MB)
  bf16_t* wqb  = (bf16_t*)(ws + 8388608);             // 3072*1024  (6 MB)
  bf16_t* wob  = (bf16_t*)(ws + 14680064);            // 1024*1024  (2 MB)
  bf16_t* qkvb = (bf16_t*)(ws + 16777216);            // 4096*3072  (24 MB)
  bf16_t* aob  = (bf16_t*)(ws + 41943040);            // 4096*1024  (8 MB)

  cvt3_f32_bf16<<<4096, 256, 0, stream>>>(x, w_qkv, w_out, xb);

  // gemm1: M=4096 N=3072 -> 32x24 = 768 blocks, 8x12 rectangle per XCD
  gemm_tn<<<768, 256, 0, stream>>>(xb, wqb, qkvb, 1024, 3072,
                                   1024, 0.18033688011f);

  flash_attn<<<512, 512, 0, stream>>>(qkvb, aob);

  // gemm2: M=4096 N=1024, BN=64 -> 32x16 = 512 blocks, 8x8 rectangle per XCD
  gemm_tn_n64<<<512, 256, 0, stream>>>(aob, wob, (float*)d_out, b_out,
                                       1024, 1024);
}